// Round 1
// 152.884 us; speedup vs baseline: 1.0097x; 1.0097x over previous
//
#include <hip/hip_runtime.h>
#include <math.h>

typedef float f4 __attribute__((ext_vector_type(4)));
typedef float f2 __attribute__((ext_vector_type(2)));

__constant__ float c_ytab[64] = {
  16.f,11.f,10.f,16.f,24.f,40.f,51.f,61.f,
  12.f,12.f,14.f,19.f,26.f,58.f,60.f,55.f,
  14.f,13.f,16.f,24.f,40.f,57.f,69.f,56.f,
  14.f,17.f,22.f,29.f,51.f,87.f,80.f,62.f,
  18.f,22.f,37.f,56.f,68.f,109.f,103.f,77.f,
  24.f,35.f,55.f,64.f,81.f,104.f,113.f,92.f,
  49.f,64.f,78.f,87.f,103.f,121.f,120.f,101.f,
  72.f,92.f,95.f,98.f,112.f,100.f,103.f,99.f};

__constant__ float c_ctab[64] = {
  17.f,18.f,24.f,47.f,99.f,99.f,99.f,99.f,
  18.f,21.f,26.f,66.f,99.f,99.f,99.f,99.f,
  24.f,26.f,56.f,99.f,99.f,99.f,99.f,99.f,
  47.f,66.f,99.f,99.f,99.f,99.f,99.f,99.f,
  99.f,99.f,99.f,99.f,99.f,99.f,99.f,99.f,
  99.f,99.f,99.f,99.f,99.f,99.f,99.f,99.f,
  99.f,99.f,99.f,99.f,99.f,99.f,99.f,99.f,
  99.f,99.f,99.f,99.f,99.f,99.f,99.f,99.f};

// One block = 64x16 pixel tile of one image (H=W=512):
//   16 Y 8x8 blocks (2 rows x 8 cols), 4 Cb + 4 Cr 8x8 blocks (pooled 8x32).
// Chroma 2x2 pooling in-register via __shfl_xor(16). 2 barriers.
// All DCT-phase LDS traffic is ds_read_b128/ds_write_b128:
//   s_C  [8][12] : C[j][v]*0.25*alpha_v  (pass-1 coefs, f4 over v; rows 48B)
//   s_CT [8][8]  : C[j][u]*alpha_u at [u][j] (pass-2 coefs, f4 over j)
//   s_ty/[s_tc]  : temps laid out [blk][x*8+v] (blk stride 72 to stagger banks)
//                  -> pass-1 writes f4 (4 consecutive v), pass-2 reads f4 over j.
// Scale factors folded into coef tables; +-128 bias removed (chroma stores
// unshifted, Y DC term adjusted by -1024*0.25*alpha0 = -181.0193359...).
__global__ __launch_bounds__(256) void jpeg_kernel(
    const float* __restrict__ x, const float* __restrict__ factor,
    float* __restrict__ out, int B)
{
    __shared__ __align__(16) float s_y [16][68];   // Y pixels (64 wide, +4 pad)
    __shared__ __align__(16) float s_cp[2][8][36]; // pooled chroma-128, 8x32 (+4 pad)
    __shared__ __align__(16) float s_ty[16][72];   // Y pass-1 temp: [blk][x*8+v]
    __shared__ __align__(16) float s_tc[2][4][72]; // chroma pass-1 temp
    __shared__ __align__(16) float s_C [8][12];    // pass-1 coefs (scaled)
    __shared__ __align__(16) float s_CT[8][8];     // pass-2 coefs (scaled, transposed)
    __shared__ __align__(16) float s_qy[64];       // 1/(Y_TABLE*f)
    __shared__ __align__(16) float s_qc[64];       // 1/(C_TABLE*f)

    const int t      = threadIdx.x;
    const int b      = blockIdx.x >> 8;    // image (256 tiles/image)
    const int rem    = blockIdx.x & 255;
    const int tile_y = rem >> 3;           // 0..31
    const int tile_x = rem & 7;            // 0..7

    const float f = factor[b];
    if (t < 64) {
        int jj = t >> 3, vv = t & 7;
        float c  = cosf((float)((2*jj+1)*vv) * 0.19634954084936207f); // pi/16
        float al = (vv == 0) ? 0.70710678118654752f : 1.0f;
        s_C [jj][vv] = c * 0.25f * al;   // pass-1: fold 0.25*alpha_v
        s_CT[vv][jj] = c * al;           // pass-2: fold alpha_u, transposed
    } else if (t < 128) {
        s_qy[t - 64] = 1.0f / (c_ytab[t - 64] * f);
    } else if (t < 192) {
        s_qc[t - 128] = 1.0f / (c_ctab[t - 128] * f);
    }

    // ---- Phase A: load (nt), RGB->YCbCr, Y->LDS, chroma pool in-register ---
    {
        const int row = t >> 4;            // 0..15
        const int col = (t & 15) << 2;     // 0..60
        const int gy  = tile_y * 16 + row;
        const int gx  = (tile_x << 6) + col;
        const float* px = x + ((size_t)b * 3 * 512 + gy) * 512 + gx;
        f4 r4 = __builtin_nontemporal_load((const f4*)(px));
        f4 g4 = __builtin_nontemporal_load((const f4*)(px + 262144));
        f4 b4 = __builtin_nontemporal_load((const f4*)(px + 524288));
        f4 yv, cbv, crv;
        // NOTE: no +128 on chroma -- it would be subtracted again by the DCT.
        #define CC(i) { \
            float R = r4[i]*255.0f, G = g4[i]*255.0f, Bl = b4[i]*255.0f; \
            yv[i]  =  0.299f*R + 0.587f*G + 0.114f*Bl; \
            cbv[i] = -0.168736f*R - 0.331264f*G + 0.5f*Bl; \
            crv[i] =  0.5f*R - 0.418688f*G - 0.081312f*Bl; }
        CC(0); CC(1); CC(2); CC(3);
        #undef CC
        *(f4*)&s_y[row][col] = yv;
        float cb01 = cbv[0] + cbv[1], cb23 = cbv[2] + cbv[3];
        float cr01 = crv[0] + crv[1], cr23 = crv[2] + crv[3];
        float cb01o = __shfl_xor(cb01, 16, 64);
        float cb23o = __shfl_xor(cb23, 16, 64);
        float cr01o = __shfl_xor(cr01, 16, 64);
        float cr23o = __shfl_xor(cr23, 16, 64);
        if ((row & 1) == 0) {
            int prow = row >> 1;           // 0..7
            int pcol = (t & 15) << 1;      // 0..30
            f2 cbp = { 0.25f*(cb01 + cb01o), 0.25f*(cb23 + cb23o) };
            f2 crp = { 0.25f*(cr01 + cr01o), 0.25f*(cr23 + cr23o) };
            *(f2*)&s_cp[0][prow][pcol] = cbp;
            *(f2*)&s_cp[1][prow][pcol] = crp;
        }
    }
    __syncthreads();

    // ---- Phase B: DCT pass 1 (rows -> v), all-f4 LDS traffic --------------
    {   // Y: thread (blk, x, v0) computes t[x][v0..v0+3], one f4 write
        const int blk = t >> 4;            // 0..15
        const int xx  = (t >> 1) & 7;
        const int v0  = (t & 1) << 2;      // 0 or 4
        const int by = blk >> 3, bx = blk & 7;
        const float* ar = &s_y[by*8 + xx][bx*8];
        f4 q0 = *(const f4*)ar;
        f4 q1 = *(const f4*)(ar + 4);
        float a[8] = {q0[0], q0[1], q0[2], q0[3], q1[0], q1[1], q1[2], q1[3]};
        f4 acc = a[0] * *(const f4*)&s_C[0][v0];
        #pragma unroll
        for (int j = 1; j < 8; ++j)
            acc += a[j] * *(const f4*)&s_C[j][v0];
        // DC adjustment for the dropped (pixel-128): 128*8*0.25*alpha0
        if (v0 == 0) acc[0] -= 181.01933598375617f;
        *(f4*)&s_ty[blk][xx*8 + v0] = acc;
    }
    if (t < 128) {  // chroma: thread (ch, blk, x, v0), same shape as Y
        const int ch  = t >> 6;
        const int tt  = t & 63;
        const int blk = tt >> 4;           // 0..3
        const int xx  = (tt >> 1) & 7;
        const int v0  = (tt & 1) << 2;
        const float* ar = &s_cp[ch][xx][blk*8];
        f4 q0 = *(const f4*)ar;
        f4 q1 = *(const f4*)(ar + 4);
        float a[8] = {q0[0], q0[1], q0[2], q0[3], q1[0], q1[1], q1[2], q1[3]};
        f4 acc = a[0] * *(const f4*)&s_C[0][v0];
        #pragma unroll
        for (int j = 1; j < 8; ++j)
            acc += a[j] * *(const f4*)&s_C[j][v0];
        // no DC adjustment: chroma was stored already bias-free
        *(f4*)&s_tc[ch][blk][xx*8 + v0] = acc;
    }
    __syncthreads();

    // ---- Phase C: DCT pass 2 (cols -> u), quantize, diff_round, store (nt) -
    {   // Y: 4 outputs per thread; 8 f4 temp reads + 2 f4 coef reads
        const int blk = t >> 4;
        const int u   = (t >> 1) & 7;
        const int v0  = (t & 1) << 2;
        const int by = blk >> 3, bx = blk & 7;
        f4 c0 = *(const f4*)&s_CT[u][0];
        f4 c1 = *(const f4*)&s_CT[u][4];
        const float* tp = &s_ty[blk][v0];
        f4 acc =  c0[0] * *(const f4*)(tp);
        acc    += c0[1] * *(const f4*)(tp + 8);
        acc    += c0[2] * *(const f4*)(tp + 16);
        acc    += c0[3] * *(const f4*)(tp + 24);
        acc    += c1[0] * *(const f4*)(tp + 32);
        acc    += c1[1] * *(const f4*)(tp + 40);
        acc    += c1[2] * *(const f4*)(tp + 48);
        acc    += c1[3] * *(const f4*)(tp + 56);
        f4 q = acc * *(const f4*)&s_qy[u*8 + v0];
        f4 res;
        #pragma unroll
        for (int k = 0; k < 4; ++k) {
            float r = rintf(q[k]);          // round-half-even == jnp.round
            float d = q[k] - r;
            res[k] = r + d * d * d;         // diff_round
        }
        size_t n = (size_t)b * 4096 + (size_t)(tile_y*2 + by) * 64 + (tile_x*8 + bx);
        __builtin_nontemporal_store(res, (f4*)(out + n * 64 + u*8 + v0));
    }
    if (t < 128) {  // chroma: waves 0-1, 4 outputs per thread
        const int ch  = t >> 6;            // 0=cb, 1=cr
        const int tt  = t & 63;
        const int blk = tt >> 4;           // 0..3
        const int u   = (tt >> 1) & 7;
        const int v0  = (tt & 1) << 2;     // 0 or 4
        f4 c0 = *(const f4*)&s_CT[u][0];
        f4 c1 = *(const f4*)&s_CT[u][4];
        const float* tp = &s_tc[ch][blk][v0];
        f4 acc =  c0[0] * *(const f4*)(tp);
        acc    += c0[1] * *(const f4*)(tp + 8);
        acc    += c0[2] * *(const f4*)(tp + 16);
        acc    += c0[3] * *(const f4*)(tp + 24);
        acc    += c1[0] * *(const f4*)(tp + 32);
        acc    += c1[1] * *(const f4*)(tp + 40);
        acc    += c1[2] * *(const f4*)(tp + 48);
        acc    += c1[3] * *(const f4*)(tp + 56);
        f4 q = acc * *(const f4*)&s_qc[u*8 + v0];
        f4 res;
        #pragma unroll
        for (int k = 0; k < 4; ++k) {
            float r = rintf(q[k]);
            float d = q[k] - r;
            res[k] = r + d * d * d;
        }
        size_t base = (size_t)B * 262144 + (size_t)ch * (size_t)B * 65536;
        size_t n    = (size_t)b * 1024 + tile_y * 32 + tile_x * 4 + blk;
        __builtin_nontemporal_store(res, (f4*)(out + base + n * 64 + u*8 + v0));
    }
}

extern "C" void kernel_launch(void* const* d_in, const int* in_sizes, int n_in,
                              void* d_out, int out_size, void* d_ws, size_t ws_size,
                              hipStream_t stream) {
    const float* x      = (const float*)d_in[0];
    const float* factor = (const float*)d_in[1];
    float* out          = (float*)d_out;
    const int B = in_sizes[1];
    dim3 grid(B * 256), block(256);
    jpeg_kernel<<<grid, block, 0, stream>>>(x, factor, out, B);
}